// Round 6
// baseline (309.726 us; speedup 1.0000x reference)
//
#include <hip/hip_runtime.h>
#include <cstdint>
#include <cstddef>

// GNNEncoder: 2x (edge-MLP GNN layer) + mean pool + MLP head. bf16 node pipeline, fused.
//   AB1 = x @ [W1a|W1b] + [b1|0]                      (g1_k: MFMA, fp32 in)
//   fused_k<true>:  per 64-node tile: agg(AB1) -> LDS -> H1 GEMM -> LDS -> AB2 GEMM
//   fused_k<false>: agg(AB2) -> LDS -> H2 GEMM -> global H
//   pool + head (fp32)

static constexpr int GRAPHS = 64;

using bf16x8 = __attribute__((ext_vector_type(8))) short;
using f32x4 = __attribute__((ext_vector_type(4))) float;

__device__ inline float bf2f(uint u) { return __builtin_bit_cast(float, u << 16); }
__device__ inline float bf2f_hi(uint u) { return __builtin_bit_cast(float, u & 0xffff0000u); }
__device__ inline ushort f2bf(float f) {
    uint u = __builtin_bit_cast(uint, f);
    return (ushort)((u + 0x7fffu + ((u >> 16) & 1u)) >> 16);
}

// ---------------- setup: weights cast/transpose + deg=0 + psum=0 + biases + gstart ----------
__global__ __launch_bounds__(256) void setup_k(
    const float* __restrict__ w1_1, const float* __restrict__ w2_1,
    const float* __restrict__ w1_2, const float* __restrict__ w2_2,
    const float* __restrict__ b1_1, const float* __restrict__ b2_1,
    ushort* __restrict__ wt1a, ushort* __restrict__ wt1b,
    ushort* __restrict__ wt2a, ushort* __restrict__ wt2b,
    float* __restrict__ b256_1, float* __restrict__ b256_2,
    int* __restrict__ deg, float* __restrict__ psum,
    const int* __restrict__ batch, int* __restrict__ gs, int M, int nbDeg) {
    int b = blockIdx.x, t = threadIdx.x;
    if (b < 128) {
        int i = b * 256 + t;
        int j = i >> 7, k = i & 127;
        wt1a[i] = f2bf((j < 128) ? w1_1[k * 128 + j] : w1_1[(128 + k) * 128 + (j - 128)]);
        wt1b[i] = f2bf((j < 128) ? w2_1[k * 128 + j] : w2_1[(128 + k) * 128 + (j - 128)]);
        return;
    }
    b -= 128;
    if (b < 64) {
        int i = b * 256 + t;
        int j = i >> 7, k = i & 127;
        wt2a[i] = f2bf(w1_2[k * 128 + j]);
        wt2b[i] = f2bf(w2_2[k * 128 + j]);
        return;
    }
    b -= 64;
    if (b < nbDeg) {
        int i = b * 256 + t;
        if (i < M) deg[i] = 0;
        return;
    }
    b -= nbDeg;
    if (b < 32) {
        psum[b * 256 + t] = 0.f;
        return;
    }
    b -= 32;
    if (b == 0) {
        b256_1[t] = (t < 128) ? b1_1[t] : 0.f;
        b256_2[t] = (t < 128) ? b2_1[t] : 0.f;
        return;
    }
    if (t > GRAPHS) return;
    int lo = 0, hi = M;
    while (lo < hi) {
        int mid = (lo + hi) >> 1;
        if (batch[mid] < t) lo = mid + 1;
        else hi = mid;
    }
    gs[t] = lo;
}

// ---------------- CSR build ----------------
__global__ __launch_bounds__(256) void hist_k(const int* __restrict__ dst, int* __restrict__ deg, int E) {
    int i = blockIdx.x * 256 + threadIdx.x;
    if (i < E) atomicAdd(&deg[dst[i]], 1);
}

// single-block scan: 256 threads x 160 contiguous elements each
__global__ __launch_bounds__(256) void scan_k(const int* __restrict__ deg, int* __restrict__ rp,
                                              int* __restrict__ cursor, int M) {
    __shared__ int ts[256];
    int t = threadIdx.x;
    int per = (M + 255) / 256;
    per = (per + 3) & ~3;
    int s0 = t * per;
    int s1 = s0 + per; if (s1 > M) s1 = M;
    int sum = 0;
    for (int i = s0; i < s1; i += 4) {
        int4 v = *reinterpret_cast<const int4*>(deg + i);
        sum += v.x + v.y + v.z + v.w;
    }
    ts[t] = sum;
    __syncthreads();
    for (int off = 1; off < 256; off <<= 1) {
        int v = (t >= off) ? ts[t - off] : 0;
        __syncthreads();
        ts[t] += v;
        __syncthreads();
    }
    int run = ts[t] - sum;
    for (int i = s0; i < s1; i += 4) {
        int4 v = *reinterpret_cast<const int4*>(deg + i);
        int4 o;
        o.x = run; run += v.x;
        o.y = run; run += v.y;
        o.z = run; run += v.z;
        o.w = run; run += v.w;
        *reinterpret_cast<int4*>(rp + i) = o;
        *reinterpret_cast<int4*>(cursor + i) = o;
    }
    if (t == 0) rp[M] = ts[255];
}

__global__ __launch_bounds__(256) void fill_k(const int* __restrict__ src, const int* __restrict__ dst,
                                              int* __restrict__ cursor, int* __restrict__ col, int E) {
    int i = blockIdx.x * 256 + threadIdx.x;
    if (i < E) {
        int d = dst[i];
        int p = atomicAdd(&cursor[d], 1);
        col[p] = src[i];
    }
}

// ---------------- g1: AB1[M][256](bf16) = x[M][128](f32) @ wt1a^T + [b1|0] ----------------
__global__ __launch_bounds__(256) void g1_k(const float* __restrict__ X, const ushort* __restrict__ Wt,
                                            const float* __restrict__ bias, ushort* __restrict__ Y, int M) {
    int wave = threadIdx.x >> 6, lane = threadIdx.x & 63;
    int row0 = blockIdx.x * 64 + wave * 16;
    int lr = lane & 15, lg = lane >> 4;

    const float* xrow = X + (size_t)(row0 + lr) * 128 + lg * 8;
    bf16x8 a[4];
#pragma unroll
    for (int k = 0; k < 4; ++k) {
        float4 v0 = *reinterpret_cast<const float4*>(xrow + k * 32);
        float4 v1 = *reinterpret_cast<const float4*>(xrow + k * 32 + 4);
        bf16x8 av;
        av[0] = (short)f2bf(v0.x); av[1] = (short)f2bf(v0.y);
        av[2] = (short)f2bf(v0.z); av[3] = (short)f2bf(v0.w);
        av[4] = (short)f2bf(v1.x); av[5] = (short)f2bf(v1.y);
        av[6] = (short)f2bf(v1.z); av[7] = (short)f2bf(v1.w);
        a[k] = av;
    }
    for (int n = 0; n < 16; ++n) {
        const ushort* wrow = Wt + (size_t)(n * 16 + lr) * 128 + lg * 8;
        f32x4 acc = {0.f, 0.f, 0.f, 0.f};
#pragma unroll
        for (int k = 0; k < 4; ++k) {
            bf16x8 b = *reinterpret_cast<const bf16x8*>(wrow + k * 32);
            acc = __builtin_amdgcn_mfma_f32_16x16x32_bf16(a[k], b, acc, 0, 0, 0);
        }
        int c = n * 16 + lr;
        float bv = bias[c];
#pragma unroll
        for (int r = 0; r < 4; ++r)
            Y[(size_t)(row0 + lg * 4 + r) * 256 + c] = f2bf(acc[r] + bv);
    }
}

// ---------------- fused layer: agg -> (LDS) -> H GEMM -> [LDS -> AB GEMM | global H] --------
// Block = 256 threads / 4 waves handles 64 nodes. LDS tile = 64 rows x 256 BYTES = 64*16 uint4.
// XOR swizzle: 16B-chunk index within a row ^= (row & 7).
__device__ inline void accum8(uint4 b, const float2* a, float2* acc) {
    const uint* bu = reinterpret_cast<const uint*>(&b);
#pragma unroll
    for (int j = 0; j < 4; ++j) {
        uint u = bu[j];
        acc[j].x += fmaxf(a[j].x + bf2f(u), 0.f);
        acc[j].y += fmaxf(a[j].y + bf2f_hi(u), 0.f);
    }
}

template <bool FUSE>
__global__ __launch_bounds__(256) void fused_k(const ushort* __restrict__ ABin,
                                               const int* __restrict__ rp, const int* __restrict__ col,
                                               const ushort* __restrict__ W2t, const float* __restrict__ b2,
                                               const ushort* __restrict__ W1n, const float* __restrict__ bn,
                                               ushort* __restrict__ OUT, int M) {
    __shared__ uint4 hs4[64 * 16];                      // 64 rows x 256 bytes
    __shared__ uint4 ht4[FUSE ? 64 * 16 : 16];          // second tile only when fusing
    char* hs = reinterpret_cast<char*>(hs4);
    char* ht = reinterpret_cast<char*>(ht4);

    int wave = threadIdx.x >> 6, lane = threadIdx.x & 63;
    int fs = lane & 15, lg = lane >> 4;
    int node0 = blockIdx.x * 64;

    // ---- phase 1: aggregate 16 nodes per wave ----
    for (int i = 0; i < 16; ++i) {
        int n = node0 + wave * 16 + i;
        uint4 av = *reinterpret_cast<const uint4*>(ABin + (size_t)n * 256 + fs * 8);
        float2 a[4];
        {
            const uint* au = reinterpret_cast<const uint*>(&av);
#pragma unroll
            for (int j = 0; j < 4; ++j) a[j] = make_float2(bf2f(au[j]), bf2f_hi(au[j]));
        }
        float2 acc[4] = {{0.f, 0.f}, {0.f, 0.f}, {0.f, 0.f}, {0.f, 0.f}};
        int e0 = rp[n], e1 = rp[n + 1];
        int eMain = e0 + ((e1 - e0) & ~7);
        for (int eb = e0; eb < eMain; eb += 8) {
            int sA = col[eb + lg];
            int sB = col[eb + lg + 4];
            uint4 bA = *reinterpret_cast<const uint4*>(ABin + (size_t)sA * 256 + 128 + fs * 8);
            uint4 bB = *reinterpret_cast<const uint4*>(ABin + (size_t)sB * 256 + 128 + fs * 8);
            accum8(bA, a, acc);
            accum8(bB, a, acc);
        }
        for (int e = eMain + lg; e < e1; e += 4) {
            int s = col[e];
            uint4 b = *reinterpret_cast<const uint4*>(ABin + (size_t)s * 256 + 128 + fs * 8);
            accum8(b, a, acc);
        }
#pragma unroll
        for (int j = 0; j < 4; ++j) {
            acc[j].x += __shfl_xor(acc[j].x, 16);
            acc[j].y += __shfl_xor(acc[j].y, 16);
            acc[j].x += __shfl_xor(acc[j].x, 32);
            acc[j].y += __shfl_xor(acc[j].y, 32);
        }
        if (lg == 0) {
            uint4 o;
            uint* ou = reinterpret_cast<uint*>(&o);
#pragma unroll
            for (int j = 0; j < 4; ++j)
                ou[j] = (uint)f2bf(acc[j].x) | ((uint)f2bf(acc[j].y) << 16);
            int row = wave * 16 + i;
            int chunk = fs ^ (row & 7);
            *reinterpret_cast<uint4*>(hs + row * 256 + chunk * 16) = o;
        }
    }
    __syncthreads();

    // ---- phase 2: H rows (wave's 16 rows) = relu(hs @ W2t^T + deg*b2) ----
    int r0 = wave * 16;
    int lr = fs;
    bf16x8 a2[4];
#pragma unroll
    for (int k = 0; k < 4; ++k) {
        int row = r0 + lr;
        int chunk = (lg + 4 * k) ^ (row & 7);
        a2[k] = *reinterpret_cast<const bf16x8*>(hs + row * 256 + chunk * 16);
    }
    float degf[4];
#pragma unroll
    for (int r = 0; r < 4; ++r) {
        int gr = node0 + r0 + lg * 4 + r;
        degf[r] = (float)(rp[gr + 1] - rp[gr]);
    }
    for (int nb = 0; nb < 8; ++nb) {
        const ushort* wrow = W2t + (size_t)(nb * 16 + lr) * 128 + lg * 8;
        f32x4 acc = {0.f, 0.f, 0.f, 0.f};
#pragma unroll
        for (int k = 0; k < 4; ++k) {
            bf16x8 b = *reinterpret_cast<const bf16x8*>(wrow + k * 32);
            acc = __builtin_amdgcn_mfma_f32_16x16x32_bf16(a2[k], b, acc, 0, 0, 0);
        }
        int c = nb * 16 + lr;
        float bv = b2[c];
#pragma unroll
        for (int r = 0; r < 4; ++r) {
            float v = fmaxf(acc[r] + degf[r] * bv, 0.f);
            ushort hv = f2bf(v);
            if constexpr (FUSE) {
                int row = r0 + lg * 4 + r;
                int chunk = (c >> 3) ^ (row & 7);
                *reinterpret_cast<ushort*>(ht + row * 256 + chunk * 16 + (c & 7) * 2) = hv;
            } else {
                OUT[(size_t)(node0 + r0 + lg * 4 + r) * 128 + c] = hv;
            }
        }
    }

    if constexpr (FUSE) {
        __syncthreads();
        // ---- phase 3: ABout rows = ht @ W1n^T + bn ----
        bf16x8 a3[4];
#pragma unroll
        for (int k = 0; k < 4; ++k) {
            int row = r0 + lr;
            int chunk = (lg + 4 * k) ^ (row & 7);
            a3[k] = *reinterpret_cast<const bf16x8*>(ht + row * 256 + chunk * 16);
        }
        for (int nb = 0; nb < 16; ++nb) {
            const ushort* wrow = W1n + (size_t)(nb * 16 + lr) * 128 + lg * 8;
            f32x4 acc = {0.f, 0.f, 0.f, 0.f};
#pragma unroll
            for (int k = 0; k < 4; ++k) {
                bf16x8 b = *reinterpret_cast<const bf16x8*>(wrow + k * 32);
                acc = __builtin_amdgcn_mfma_f32_16x16x32_bf16(a3[k], b, acc, 0, 0, 0);
            }
            int c = nb * 16 + lr;
            float bv = bn[c];
#pragma unroll
            for (int r = 0; r < 4; ++r)
                OUT[(size_t)(node0 + r0 + lg * 4 + r) * 256 + c] = f2bf(acc[r] + bv);
        }
    }
}

// ---------------- pooling (node-parallel, sorted batch, atomic flush at boundaries) ----------
__global__ __launch_bounds__(128) void pool_k(const ushort* __restrict__ H, const int* __restrict__ batch,
                                              float* __restrict__ psum, int M, int nblk) {
    int f = threadIdx.x;
    int chunk = (M + nblk - 1) / nblk;
    int n0 = blockIdx.x * chunk;
    int n1 = n0 + chunk;
    if (n1 > M) n1 = M;
    if (n0 >= n1) return;
    int g = batch[n0];
    float acc = 0.f;
    for (int n = n0; n < n1; ++n) {
        int bg = batch[n];
        if (bg != g) {
            atomicAdd(&psum[g * 128 + f], acc);
            acc = 0.f;
            g = bg;
        }
        acc += bf2f((uint)H[(size_t)n * 128 + f]);
    }
    atomicAdd(&psum[g * 128 + f], acc);
}

// ---------------- head MLP: relu((psum/cnt)@wm1+bm1)@wm2+bm2 -> out[64][512] (fp32) ----------
__global__ __launch_bounds__(128) void head_k(const float* __restrict__ psum,
                                              const int* __restrict__ gs,
                                              const float* __restrict__ wm1, const float* __restrict__ bm1,
                                              const float* __restrict__ wm2, const float* __restrict__ bm2,
                                              float* __restrict__ out) {
    __shared__ float p[128];
    __shared__ float h[128];
    int g = blockIdx.x, t = threadIdx.x;
    int cnt = gs[g + 1] - gs[g];
    float rcp = 1.0f / (float)(cnt > 0 ? cnt : 1);
    p[t] = psum[g * 128 + t] * rcp;
    __syncthreads();
    float a = bm1[t];
    for (int k = 0; k < 128; ++k) a += p[k] * wm1[k * 128 + t];
    h[t] = fmaxf(a, 0.f);
    __syncthreads();
    float acc[4];
#pragma unroll
    for (int j = 0; j < 4; ++j) acc[j] = bm2[j * 128 + t];
    for (int k = 0; k < 128; ++k) {
        float hv = h[k];
#pragma unroll
        for (int j = 0; j < 4; ++j) acc[j] += hv * wm2[k * 512 + j * 128 + t];
    }
#pragma unroll
    for (int j = 0; j < 4; ++j) out[(size_t)g * 512 + j * 128 + t] = acc[j];
}

extern "C" void kernel_launch(void* const* d_in, const int* in_sizes, int n_in,
                              void* d_out, int out_size, void* d_ws, size_t ws_size,
                              hipStream_t stream) {
    const float* x = (const float*)d_in[0];
    const int* ei = (const int*)d_in[1];
    const int* batch = (const int*)d_in[2];
    const float* w1_1 = (const float*)d_in[3];
    const float* b1_1 = (const float*)d_in[4];
    const float* w1_2 = (const float*)d_in[5];
    const float* b1_2 = (const float*)d_in[6];
    const float* w2_1 = (const float*)d_in[7];
    const float* b2_1 = (const float*)d_in[8];
    const float* w2_2 = (const float*)d_in[9];
    const float* b2_2 = (const float*)d_in[10];
    const float* wm1 = (const float*)d_in[11];
    const float* bm1 = (const float*)d_in[12];
    const float* wm2 = (const float*)d_in[13];
    const float* bm2 = (const float*)d_in[14];

    const int E = in_sizes[1] / 2;
    const int M = in_sizes[0] / 128;
    const int* srcp = ei;
    const int* dstp = ei + E;

    char* ws = (char*)d_ws;
    size_t off = 0;
    auto alloc = [&](size_t bytes) -> void* {
        void* p = ws + off;
        off += (bytes + 255) & ~(size_t)255;
        return p;
    };
    ushort* AB1 = (ushort*)alloc((size_t)M * 256 * 2);
    ushort* AB2 = (ushort*)alloc((size_t)M * 256 * 2);
    ushort* H = (ushort*)alloc((size_t)M * 128 * 2);
    int* rp = (int*)alloc((size_t)(M + 1) * 4);
    int* cursor = (int*)alloc((size_t)M * 4);  // reused as deg during hist
    int* col = (int*)alloc((size_t)E * 4);
    int* gs = (int*)alloc((GRAPHS + 1) * 4);
    float* psum = (float*)alloc(GRAPHS * 128 * 4);
    ushort* wt1a = (ushort*)alloc(256 * 128 * 2);
    ushort* wt1b = (ushort*)alloc(256 * 128 * 2);
    ushort* wt2a = (ushort*)alloc(128 * 128 * 2);
    ushort* wt2b = (ushort*)alloc(128 * 128 * 2);
    float* b256_1 = (float*)alloc(256 * 4);
    float* b256_2 = (float*)alloc(256 * 4);

    const int nbDeg = (M + 255) / 256;

    // 1. setup (weights, deg=0, psum=0, biases, gstart)
    setup_k<<<128 + 64 + nbDeg + 32 + 2, 256, 0, stream>>>(
        w1_1, w2_1, w1_2, w2_2, b1_1, b2_1, wt1a, wt1b, wt2a, wt2b, b256_1, b256_2,
        cursor, psum, batch, gs, M, nbDeg);
    // 2-4. CSR over dst
    hist_k<<<(E + 255) / 256, 256, 0, stream>>>(dstp, cursor, E);
    scan_k<<<1, 256, 0, stream>>>(cursor, rp, cursor, M);
    fill_k<<<(E + 255) / 256, 256, 0, stream>>>(srcp, dstp, cursor, col, E);
    // 5. layer1 edge-GEMM (fp32 x in)
    g1_k<<<M / 64, 256, 0, stream>>>(x, wt1a, b256_1, AB1, M);
    // 6. fused: agg(AB1) + H1 GEMM + AB2 GEMM
    fused_k<true><<<M / 64, 256, 0, stream>>>(AB1, rp, col, wt2a, b1_2, wt1b, b256_2, AB2, M);
    // 7. fused tail: agg(AB2) + H2 GEMM
    fused_k<false><<<M / 64, 256, 0, stream>>>(AB2, rp, col, wt2b, b2_2, nullptr, nullptr, H, M);
    // 8-9. pool + head
    pool_k<<<512, 128, 0, stream>>>(H, batch, psum, M, 512);
    head_k<<<GRAPHS, 128, 0, stream>>>(psum, gs, wm1, bm1, wm2, bm2, (float*)d_out);
}

// Round 7
// 271.417 us; speedup vs baseline: 1.1411x; 1.1411x over previous
//
#include <hip/hip_runtime.h>
#include <cstdint>
#include <cstddef>

// GNNEncoder: 2x (edge-MLP GNN layer) + mean pool + MLP head. bf16 node pipeline.
//   AB1 = x @ [W1a|W1b] + [b1|0]                       (g1_k, MFMA, fp32 in)
//   Hagg[n] = sum_{e:dst=n} relu(A[n] + B[src_e])      (agg_k, wave-per-node gather)
//   layer_k: H1 = relu(Hagg@W2a + deg*b) -> per-wave LDS -> AB2 = H1@W1b + [b|0]
//   agg_k;  H2 = relu(Hagg@W2b + deg*b)                (g2_k)
//   pool + head (fp32)
// Lesson R6: keep the latency-bound gather at wave-per-node parallelism; only fuse
// compute-local GEMM chains (LDS handoff within one wave, no barrier).

static constexpr int GRAPHS = 64;

using bf16x8 = __attribute__((ext_vector_type(8))) short;
using f32x4 = __attribute__((ext_vector_type(4))) float;

__device__ inline float bf2f(uint u) { return __builtin_bit_cast(float, u << 16); }
__device__ inline float bf2f_hi(uint u) { return __builtin_bit_cast(float, u & 0xffff0000u); }
__device__ inline ushort f2bf(float f) {
    uint u = __builtin_bit_cast(uint, f);
    return (ushort)((u + 0x7fffu + ((u >> 16) & 1u)) >> 16);
}

// ---------------- setup: weights cast/transpose + deg=0 + psum=0 + biases + gstart ----------
__global__ __launch_bounds__(256) void setup_k(
    const float* __restrict__ w1_1, const float* __restrict__ w2_1,
    const float* __restrict__ w1_2, const float* __restrict__ w2_2,
    const float* __restrict__ b1_1, const float* __restrict__ b2_1,
    ushort* __restrict__ wt1a, ushort* __restrict__ wt1b,
    ushort* __restrict__ wt2a, ushort* __restrict__ wt2b,
    float* __restrict__ b256_1, float* __restrict__ b256_2,
    int* __restrict__ deg, float* __restrict__ psum,
    const int* __restrict__ batch, int* __restrict__ gs, int M, int nbDeg) {
    int b = blockIdx.x, t = threadIdx.x;
    if (b < 128) {
        int i = b * 256 + t;
        int j = i >> 7, k = i & 127;
        wt1a[i] = f2bf((j < 128) ? w1_1[k * 128 + j] : w1_1[(128 + k) * 128 + (j - 128)]);
        wt1b[i] = f2bf((j < 128) ? w2_1[k * 128 + j] : w2_1[(128 + k) * 128 + (j - 128)]);
        return;
    }
    b -= 128;
    if (b < 64) {
        int i = b * 256 + t;
        int j = i >> 7, k = i & 127;
        wt2a[i] = f2bf(w1_2[k * 128 + j]);
        wt2b[i] = f2bf(w2_2[k * 128 + j]);
        return;
    }
    b -= 64;
    if (b < nbDeg) {
        int i = b * 256 + t;
        if (i < M) deg[i] = 0;
        return;
    }
    b -= nbDeg;
    if (b < 32) {
        psum[b * 256 + t] = 0.f;
        return;
    }
    b -= 32;
    if (b == 0) {
        b256_1[t] = (t < 128) ? b1_1[t] : 0.f;
        b256_2[t] = (t < 128) ? b2_1[t] : 0.f;
        return;
    }
    if (t > GRAPHS) return;
    int lo = 0, hi = M;
    while (lo < hi) {
        int mid = (lo + hi) >> 1;
        if (batch[mid] < t) lo = mid + 1;
        else hi = mid;
    }
    gs[t] = lo;
}

// ---------------- CSR build ----------------
__global__ __launch_bounds__(256) void hist_k(const int* __restrict__ dst, int* __restrict__ deg, int E) {
    int i = blockIdx.x * 256 + threadIdx.x;
    if (i < E) atomicAdd(&deg[dst[i]], 1);
}

__global__ __launch_bounds__(256) void scan_k(const int* __restrict__ deg, int* __restrict__ rp,
                                              int* __restrict__ cursor, int M) {
    __shared__ int ts[256];
    int t = threadIdx.x;
    int per = (M + 255) / 256;
    per = (per + 3) & ~3;
    int s0 = t * per;
    int s1 = s0 + per; if (s1 > M) s1 = M;
    int sum = 0;
    for (int i = s0; i < s1; i += 4) {
        int4 v = *reinterpret_cast<const int4*>(deg + i);
        sum += v.x + v.y + v.z + v.w;
    }
    ts[t] = sum;
    __syncthreads();
    for (int off = 1; off < 256; off <<= 1) {
        int v = (t >= off) ? ts[t - off] : 0;
        __syncthreads();
        ts[t] += v;
        __syncthreads();
    }
    int run = ts[t] - sum;
    for (int i = s0; i < s1; i += 4) {
        int4 v = *reinterpret_cast<const int4*>(deg + i);
        int4 o;
        o.x = run; run += v.x;
        o.y = run; run += v.y;
        o.z = run; run += v.z;
        o.w = run; run += v.w;
        *reinterpret_cast<int4*>(rp + i) = o;
        *reinterpret_cast<int4*>(cursor + i) = o;
    }
    if (t == 0) rp[M] = ts[255];
}

__global__ __launch_bounds__(256) void fill_k(const int* __restrict__ src, const int* __restrict__ dst,
                                              int* __restrict__ cursor, int* __restrict__ col, int E) {
    int i = blockIdx.x * 256 + threadIdx.x;
    if (i < E) {
        int d = dst[i];
        int p = atomicAdd(&cursor[d], 1);
        col[p] = src[i];
    }
}

// ---------------- g1: AB1[M][256](bf16) = x[M][128](f32) @ wt1a^T + [b1|0] ----------------
__global__ __launch_bounds__(256) void g1_k(const float* __restrict__ X, const ushort* __restrict__ Wt,
                                            const float* __restrict__ bias, ushort* __restrict__ Y, int M) {
    int wave = threadIdx.x >> 6, lane = threadIdx.x & 63;
    int row0 = blockIdx.x * 64 + wave * 16;
    int lr = lane & 15, lg = lane >> 4;

    const float* xrow = X + (size_t)(row0 + lr) * 128 + lg * 8;
    bf16x8 a[4];
#pragma unroll
    for (int k = 0; k < 4; ++k) {
        float4 v0 = *reinterpret_cast<const float4*>(xrow + k * 32);
        float4 v1 = *reinterpret_cast<const float4*>(xrow + k * 32 + 4);
        bf16x8 av;
        av[0] = (short)f2bf(v0.x); av[1] = (short)f2bf(v0.y);
        av[2] = (short)f2bf(v0.z); av[3] = (short)f2bf(v0.w);
        av[4] = (short)f2bf(v1.x); av[5] = (short)f2bf(v1.y);
        av[6] = (short)f2bf(v1.z); av[7] = (short)f2bf(v1.w);
        a[k] = av;
    }
    for (int n = 0; n < 16; ++n) {
        const ushort* wrow = Wt + (size_t)(n * 16 + lr) * 128 + lg * 8;
        f32x4 acc = {0.f, 0.f, 0.f, 0.f};
#pragma unroll
        for (int k = 0; k < 4; ++k) {
            bf16x8 b = *reinterpret_cast<const bf16x8*>(wrow + k * 32);
            acc = __builtin_amdgcn_mfma_f32_16x16x32_bf16(a[k], b, acc, 0, 0, 0);
        }
        int c = n * 16 + lr;
        float bv = bias[c];
#pragma unroll
        for (int r = 0; r < 4; ++r)
            Y[(size_t)(row0 + lg * 4 + r) * 256 + c] = f2bf(acc[r] + bv);
    }
}

// ---------------- edge aggregation: Hagg[n] = sum relu(A[n] + B[src]) (wave per node) -------
__device__ inline void accum8(uint4 b, const float2* a, float2* acc) {
    const uint* bu = reinterpret_cast<const uint*>(&b);
#pragma unroll
    for (int j = 0; j < 4; ++j) {
        uint u = bu[j];
        acc[j].x += fmaxf(a[j].x + bf2f(u), 0.f);
        acc[j].y += fmaxf(a[j].y + bf2f_hi(u), 0.f);
    }
}

__global__ __launch_bounds__(256) void agg_k(const ushort* __restrict__ AB,
                                             const int* __restrict__ rp, const int* __restrict__ col,
                                             ushort* __restrict__ Hagg, int M) {
    int wave = threadIdx.x >> 6;
    int lane = threadIdx.x & 63;
    int n = blockIdx.x * 4 + wave;
    if (n >= M) return;
    int fs = lane & 15;
    int lg = lane >> 4;

    uint4 av = *reinterpret_cast<const uint4*>(AB + (size_t)n * 256 + fs * 8);
    float2 a[4];
    {
        const uint* au = reinterpret_cast<const uint*>(&av);
#pragma unroll
        for (int j = 0; j < 4; ++j) a[j] = make_float2(bf2f(au[j]), bf2f_hi(au[j]));
    }
    float2 acc[4] = {{0.f, 0.f}, {0.f, 0.f}, {0.f, 0.f}, {0.f, 0.f}};

    int e0 = rp[n], e1 = rp[n + 1];
    int eMain = e0 + ((e1 - e0) & ~7);

    for (int eb = e0; eb < eMain; eb += 8) {
        int sA = col[eb + lg];
        int sB = col[eb + lg + 4];
        uint4 bA = *reinterpret_cast<const uint4*>(AB + (size_t)sA * 256 + 128 + fs * 8);
        uint4 bB = *reinterpret_cast<const uint4*>(AB + (size_t)sB * 256 + 128 + fs * 8);
        accum8(bA, a, acc);
        accum8(bB, a, acc);
    }
    for (int e = eMain + lg; e < e1; e += 4) {
        int s = col[e];
        uint4 b = *reinterpret_cast<const uint4*>(AB + (size_t)s * 256 + 128 + fs * 8);
        accum8(b, a, acc);
    }

#pragma unroll
    for (int j = 0; j < 4; ++j) {
        acc[j].x += __shfl_xor(acc[j].x, 16);
        acc[j].y += __shfl_xor(acc[j].y, 16);
        acc[j].x += __shfl_xor(acc[j].x, 32);
        acc[j].y += __shfl_xor(acc[j].y, 32);
    }
    if (lg == 0) {
        uint4 o;
        uint* ou = reinterpret_cast<uint*>(&o);
#pragma unroll
        for (int j = 0; j < 4; ++j)
            ou[j] = (uint)f2bf(acc[j].x) | ((uint)f2bf(acc[j].y) << 16);
        *reinterpret_cast<uint4*>(Hagg + (size_t)n * 128 + fs * 8) = o;
    }
}

// ---------------- layer_k: H1 = relu(Hagg@W2t^T + deg*b2) -> (wave LDS) -> AB2 = H1@W1n^T+bn --
// Per-wave 16-row LDS tile (4 KB), XOR swizzle chunk^=(row&7); no barrier (same-wave RAW).
__global__ __launch_bounds__(256) void layer_k(const ushort* __restrict__ Hagg,
                                               const int* __restrict__ rp,
                                               const ushort* __restrict__ W2t, const float* __restrict__ b2,
                                               const ushort* __restrict__ W1n, const float* __restrict__ bn,
                                               ushort* __restrict__ ABout, int M) {
    __shared__ uint4 lds4[4 * 16 * 16];  // 4 waves x 16 rows x 256 B
    int wave = threadIdx.x >> 6, lane = threadIdx.x & 63;
    int lr = lane & 15, lg = lane >> 4;
    int row0 = blockIdx.x * 64 + wave * 16;
    char* ht = reinterpret_cast<char*>(lds4 + wave * 256);

    // A-fragments of Hagg (wave's 16 rows)
    const ushort* hrow = Hagg + (size_t)(row0 + lr) * 128 + lg * 8;
    bf16x8 a[4];
#pragma unroll
    for (int k = 0; k < 4; ++k) a[k] = *reinterpret_cast<const bf16x8*>(hrow + k * 32);

    float degf[4];
#pragma unroll
    for (int r = 0; r < 4; ++r) {
        int gr = row0 + lg * 4 + r;
        degf[r] = (float)(rp[gr + 1] - rp[gr]);
    }

    // GEMM1 -> H1 tile in LDS
    for (int nb = 0; nb < 8; ++nb) {
        const ushort* wrow = W2t + (size_t)(nb * 16 + lr) * 128 + lg * 8;
        f32x4 acc = {0.f, 0.f, 0.f, 0.f};
#pragma unroll
        for (int k = 0; k < 4; ++k) {
            bf16x8 b = *reinterpret_cast<const bf16x8*>(wrow + k * 32);
            acc = __builtin_amdgcn_mfma_f32_16x16x32_bf16(a[k], b, acc, 0, 0, 0);
        }
        int c = nb * 16 + lr;
        float bv = b2[c];
#pragma unroll
        for (int r = 0; r < 4; ++r) {
            float v = fmaxf(acc[r] + degf[r] * bv, 0.f);
            int row = lg * 4 + r;
            int chunk = (c >> 3) ^ (row & 7);
            *reinterpret_cast<ushort*>(ht + row * 256 + chunk * 16 + (c & 7) * 2) = f2bf(v);
        }
    }

    // A-fragments of H1 from LDS (same wave wrote them; compiler inserts lgkmcnt)
    bf16x8 a2[4];
#pragma unroll
    for (int k = 0; k < 4; ++k) {
        int chunk = (lg + 4 * k) ^ (lr & 7);
        a2[k] = *reinterpret_cast<const bf16x8*>(ht + lr * 256 + chunk * 16);
    }

    // GEMM2 -> ABout
    for (int nb = 0; nb < 16; ++nb) {
        const ushort* wrow = W1n + (size_t)(nb * 16 + lr) * 128 + lg * 8;
        f32x4 acc = {0.f, 0.f, 0.f, 0.f};
#pragma unroll
        for (int k = 0; k < 4; ++k) {
            bf16x8 b = *reinterpret_cast<const bf16x8*>(wrow + k * 32);
            acc = __builtin_amdgcn_mfma_f32_16x16x32_bf16(a2[k], b, acc, 0, 0, 0);
        }
        int c = nb * 16 + lr;
        float bv = bn[c];
#pragma unroll
        for (int r = 0; r < 4; ++r)
            ABout[(size_t)(row0 + lg * 4 + r) * 256 + c] = f2bf(acc[r] + bv);
    }
}

// ---------------- g2: H[M][128](bf16) = relu(Hagg@W2t^T + deg*b2) ----------------
__global__ __launch_bounds__(256) void g2_k(const ushort* __restrict__ Hagg, const ushort* __restrict__ Wt,
                                            const float* __restrict__ bias, const int* __restrict__ rp,
                                            ushort* __restrict__ Y, int M) {
    int wave = threadIdx.x >> 6, lane = threadIdx.x & 63;
    int row0 = blockIdx.x * 64 + wave * 16;
    int lr = lane & 15, lg = lane >> 4;

    const ushort* xrow = Hagg + (size_t)(row0 + lr) * 128 + lg * 8;
    bf16x8 a[4];
#pragma unroll
    for (int k = 0; k < 4; ++k) a[k] = *reinterpret_cast<const bf16x8*>(xrow + k * 32);

    float degf[4];
#pragma unroll
    for (int r = 0; r < 4; ++r) {
        int gr = row0 + lg * 4 + r;
        degf[r] = (float)(rp[gr + 1] - rp[gr]);
    }
    for (int n = 0; n < 8; ++n) {
        const ushort* wrow = Wt + (size_t)(n * 16 + lr) * 128 + lg * 8;
        f32x4 acc = {0.f, 0.f, 0.f, 0.f};
#pragma unroll
        for (int k = 0; k < 4; ++k) {
            bf16x8 b = *reinterpret_cast<const bf16x8*>(wrow + k * 32);
            acc = __builtin_amdgcn_mfma_f32_16x16x32_bf16(a[k], b, acc, 0, 0, 0);
        }
        int c = n * 16 + lr;
        float bv = bias[c];
#pragma unroll
        for (int r = 0; r < 4; ++r) {
            float v = fmaxf(acc[r] + degf[r] * bv, 0.f);
            Y[(size_t)(row0 + lg * 4 + r) * 128 + c] = f2bf(v);
        }
    }
}

// ---------------- pooling (node-parallel, sorted batch, atomic flush at boundaries) ----------
__global__ __launch_bounds__(128) void pool_k(const ushort* __restrict__ H, const int* __restrict__ batch,
                                              float* __restrict__ psum, int M, int nblk) {
    int f = threadIdx.x;
    int chunk = (M + nblk - 1) / nblk;
    int n0 = blockIdx.x * chunk;
    int n1 = n0 + chunk;
    if (n1 > M) n1 = M;
    if (n0 >= n1) return;
    int g = batch[n0];
    float acc = 0.f;
    for (int n = n0; n < n1; ++n) {
        int bg = batch[n];
        if (bg != g) {
            atomicAdd(&psum[g * 128 + f], acc);
            acc = 0.f;
            g = bg;
        }
        acc += bf2f((uint)H[(size_t)n * 128 + f]);
    }
    atomicAdd(&psum[g * 128 + f], acc);
}

// ---------------- head MLP ----------------
__global__ __launch_bounds__(128) void head_k(const float* __restrict__ psum,
                                              const int* __restrict__ gs,
                                              const float* __restrict__ wm1, const float* __restrict__ bm1,
                                              const float* __restrict__ wm2, const float* __restrict__ bm2,
                                              float* __restrict__ out) {
    __shared__ float p[128];
    __shared__ float h[128];
    int g = blockIdx.x, t = threadIdx.x;
    int cnt = gs[g + 1] - gs[g];
    float rcp = 1.0f / (float)(cnt > 0 ? cnt : 1);
    p[t] = psum[g * 128 + t] * rcp;
    __syncthreads();
    float a = bm1[t];
    for (int k = 0; k < 128; ++k) a += p[k] * wm1[k * 128 + t];
    h[t] = fmaxf(a, 0.f);
    __syncthreads();
    float acc[4];
#pragma unroll
    for (int j = 0; j < 4; ++j) acc[j] = bm2[j * 128 + t];
    for (int k = 0; k < 128; ++k) {
        float hv = h[k];
#pragma unroll
        for (int j = 0; j < 4; ++j) acc[j] += hv * wm2[k * 512 + j * 128 + t];
    }
#pragma unroll
    for (int j = 0; j < 4; ++j) out[(size_t)g * 512 + j * 128 + t] = acc[j];
}

extern "C" void kernel_launch(void* const* d_in, const int* in_sizes, int n_in,
                              void* d_out, int out_size, void* d_ws, size_t ws_size,
                              hipStream_t stream) {
    const float* x = (const float*)d_in[0];
    const int* ei = (const int*)d_in[1];
    const int* batch = (const int*)d_in[2];
    const float* w1_1 = (const float*)d_in[3];
    const float* b1_1 = (const float*)d_in[4];
    const float* w1_2 = (const float*)d_in[5];
    const float* b1_2 = (const float*)d_in[6];
    const float* w2_1 = (const float*)d_in[7];
    const float* b2_1 = (const float*)d_in[8];
    const float* w2_2 = (const float*)d_in[9];
    const float* b2_2 = (const float*)d_in[10];
    const float* wm1 = (const float*)d_in[11];
    const float* bm1 = (const float*)d_in[12];
    const float* wm2 = (const float*)d_in[13];
    const float* bm2 = (const float*)d_in[14];

    const int E = in_sizes[1] / 2;
    const int M = in_sizes[0] / 128;
    const int* srcp = ei;
    const int* dstp = ei + E;

    char* ws = (char*)d_ws;
    size_t off = 0;
    auto alloc = [&](size_t bytes) -> void* {
        void* p = ws + off;
        off += (bytes + 255) & ~(size_t)255;
        return p;
    };
    ushort* AB1 = (ushort*)alloc((size_t)M * 256 * 2);
    ushort* AB2 = (ushort*)alloc((size_t)M * 256 * 2);
    ushort* Hagg = (ushort*)alloc((size_t)M * 128 * 2);
    ushort* H = (ushort*)alloc((size_t)M * 128 * 2);
    int* rp = (int*)alloc((size_t)(M + 1) * 4);
    int* cursor = (int*)alloc((size_t)M * 4);  // reused as deg during hist
    int* col = (int*)alloc((size_t)E * 4);
    int* gs = (int*)alloc((GRAPHS + 1) * 4);
    float* psum = (float*)alloc(GRAPHS * 128 * 4);
    ushort* wt1a = (ushort*)alloc(256 * 128 * 2);
    ushort* wt1b = (ushort*)alloc(256 * 128 * 2);
    ushort* wt2a = (ushort*)alloc(128 * 128 * 2);
    ushort* wt2b = (ushort*)alloc(128 * 128 * 2);
    float* b256_1 = (float*)alloc(256 * 4);
    float* b256_2 = (float*)alloc(256 * 4);

    const int nbDeg = (M + 255) / 256;

    // 1. setup (weights, deg=0, psum=0, biases, gstart)
    setup_k<<<128 + 64 + nbDeg + 32 + 2, 256, 0, stream>>>(
        w1_1, w2_1, w1_2, w2_2, b1_1, b2_1, wt1a, wt1b, wt2a, wt2b, b256_1, b256_2,
        cursor, psum, batch, gs, M, nbDeg);
    // 2-4. CSR over dst
    hist_k<<<(E + 255) / 256, 256, 0, stream>>>(dstp, cursor, E);
    scan_k<<<1, 256, 0, stream>>>(cursor, rp, cursor, M);
    fill_k<<<(E + 255) / 256, 256, 0, stream>>>(srcp, dstp, cursor, col, E);
    // 5. layer1 edge-GEMM (fp32 x in)
    g1_k<<<M / 64, 256, 0, stream>>>(x, wt1a, b256_1, AB1, M);
    // 6. layer1 aggregate (wave per node)
    agg_k<<<(M + 3) / 4, 256, 0, stream>>>(AB1, rp, col, Hagg, M);
    // 7. layer1 H-GEMM + layer2 edge-GEMM (fused, per-wave LDS)
    layer_k<<<M / 64, 256, 0, stream>>>(Hagg, rp, wt2a, b1_2, wt1b, b256_2, AB2, M);
    // 8. layer2 aggregate
    agg_k<<<(M + 3) / 4, 256, 0, stream>>>(AB2, rp, col, Hagg, M);
    // 9. layer2 H-GEMM
    g2_k<<<M / 64, 256, 0, stream>>>(Hagg, wt2b, b2_2, rp, H, M);
    // 10-11. pool + head
    pool_k<<<512, 128, 0, stream>>>(H, batch, psum, M, 512);
    head_k<<<GRAPHS, 128, 0, stream>>>(psum, gs, wm1, bm1, wm2, bm2, (float*)d_out);
}

// Round 8
// 238.401 us; speedup vs baseline: 1.2992x; 1.1385x over previous
//
#include <hip/hip_runtime.h>
#include <cstdint>
#include <cstddef>

// GNNEncoder: 2x (edge-MLP GNN layer) + mean pool + MLP head. bf16 node pipeline.
//   AB1 = x @ [W1a|W1b] + [b1|0]                       (ngemm, fp32-in staging)
//   Hagg[n] = sum_{e:dst=n} relu(A[n] + B[src_e])      (agg_k, wave-per-node gather)
//   H1 = relu(Hagg@W2a + deg*b)                         (ngemm 128)
//   AB2 = H1 @ [W2_1a|W2_1b] + [b2|0]                   (ngemm 256)
//   agg; H2 = relu(Hagg@W2b + deg*b)                    (ngemm 128)
//   pool + head (fp32)
// ngemm uses SWAPPED MFMA operands (A=W rows, B=X rows) so each lane's 4 acc
// regs are 4 consecutive output cols of one row -> vectorized ushort4 stores.
// 64 rows/wave from an LDS X-tile (padded stride 17*16B) -> 16 MFMA per W-load.

static constexpr int GRAPHS = 64;

using bf16x8 = __attribute__((ext_vector_type(8))) short;
using f32x4 = __attribute__((ext_vector_type(4))) float;

__device__ inline float bf2f(uint u) { return __builtin_bit_cast(float, u << 16); }
__device__ inline float bf2f_hi(uint u) { return __builtin_bit_cast(float, u & 0xffff0000u); }
__device__ inline ushort f2bf(float f) {
    uint u = __builtin_bit_cast(uint, f);
    return (ushort)((u + 0x7fffu + ((u >> 16) & 1u)) >> 16);
}

// ---------------- setup: weights cast/transpose + deg=0 + psum=0 + biases + gstart ----------
__global__ __launch_bounds__(256) void setup_k(
    const float* __restrict__ w1_1, const float* __restrict__ w2_1,
    const float* __restrict__ w1_2, const float* __restrict__ w2_2,
    const float* __restrict__ b1_1, const float* __restrict__ b2_1,
    ushort* __restrict__ wt1a, ushort* __restrict__ wt1b,
    ushort* __restrict__ wt2a, ushort* __restrict__ wt2b,
    float* __restrict__ b256_1, float* __restrict__ b256_2,
    int* __restrict__ deg, float* __restrict__ psum,
    const int* __restrict__ batch, int* __restrict__ gs, int M, int nbDeg) {
    int b = blockIdx.x, t = threadIdx.x;
    if (b < 128) {
        int i = b * 256 + t;
        int j = i >> 7, k = i & 127;
        wt1a[i] = f2bf((j < 128) ? w1_1[k * 128 + j] : w1_1[(128 + k) * 128 + (j - 128)]);
        wt1b[i] = f2bf((j < 128) ? w2_1[k * 128 + j] : w2_1[(128 + k) * 128 + (j - 128)]);
        return;
    }
    b -= 128;
    if (b < 64) {
        int i = b * 256 + t;
        int j = i >> 7, k = i & 127;
        wt2a[i] = f2bf(w1_2[k * 128 + j]);
        wt2b[i] = f2bf(w2_2[k * 128 + j]);
        return;
    }
    b -= 64;
    if (b < nbDeg) {
        int i = b * 256 + t;
        if (i < M) deg[i] = 0;
        return;
    }
    b -= nbDeg;
    if (b < 32) {
        psum[b * 256 + t] = 0.f;
        return;
    }
    b -= 32;
    if (b == 0) {
        b256_1[t] = (t < 128) ? b1_1[t] : 0.f;
        b256_2[t] = (t < 128) ? b2_1[t] : 0.f;
        return;
    }
    if (t > GRAPHS) return;
    int lo = 0, hi = M;
    while (lo < hi) {
        int mid = (lo + hi) >> 1;
        if (batch[mid] < t) lo = mid + 1;
        else hi = mid;
    }
    gs[t] = lo;
}

// ---------------- CSR build ----------------
__global__ __launch_bounds__(256) void hist_k(const int* __restrict__ dst, int* __restrict__ deg, int E) {
    int i = blockIdx.x * 256 + threadIdx.x;
    if (i < E) atomicAdd(&deg[dst[i]], 1);
}

__global__ __launch_bounds__(256) void scan_k(const int* __restrict__ deg, int* __restrict__ rp,
                                              int* __restrict__ cursor, int M) {
    __shared__ int ts[256];
    int t = threadIdx.x;
    int per = (M + 255) / 256;
    per = (per + 3) & ~3;
    int s0 = t * per;
    int s1 = s0 + per; if (s1 > M) s1 = M;
    int sum = 0;
    for (int i = s0; i < s1; i += 4) {
        int4 v = *reinterpret_cast<const int4*>(deg + i);
        sum += v.x + v.y + v.z + v.w;
    }
    ts[t] = sum;
    __syncthreads();
    for (int off = 1; off < 256; off <<= 1) {
        int v = (t >= off) ? ts[t - off] : 0;
        __syncthreads();
        ts[t] += v;
        __syncthreads();
    }
    int run = ts[t] - sum;
    for (int i = s0; i < s1; i += 4) {
        int4 v = *reinterpret_cast<const int4*>(deg + i);
        int4 o;
        o.x = run; run += v.x;
        o.y = run; run += v.y;
        o.z = run; run += v.z;
        o.w = run; run += v.w;
        *reinterpret_cast<int4*>(rp + i) = o;
        *reinterpret_cast<int4*>(cursor + i) = o;
    }
    if (t == 0) rp[M] = ts[255];
}

__global__ __launch_bounds__(256) void fill_k(const int* __restrict__ src, const int* __restrict__ dst,
                                              int* __restrict__ cursor, int* __restrict__ col, int E) {
    int i = blockIdx.x * 256 + threadIdx.x;
    if (i < E) {
        int d = dst[i];
        int p = atomicAdd(&cursor[d], 1);
        col[p] = src[i];
    }
}

// ---------------- ngemm: Y[M][NOUT](bf16) = Xin[M][128] @ Wt[NOUT][128]^T (+bias[*deg])(relu)
// Swapped MFMA: A-frag=Wt rows (out cols), B-frag=X rows (out rows). Per block: 64 rows.
// LDS tile: 64 rows x 16 uint4 chunks, row stride 17 (pad) -> <=2-way bank alias.
// Wave w covers all 64 rows x col-blocks [w*NBW .. w*NBW+NBW).
template <int NOUT, bool RELU, bool DEGBIAS, bool F32IN>
__global__ __launch_bounds__(256) void ngemm_k(const void* __restrict__ Xin,
                                               const ushort* __restrict__ Wt,
                                               const float* __restrict__ bias,
                                               const int* __restrict__ rp,
                                               ushort* __restrict__ Y, int M) {
    __shared__ uint4 xt[64 * 17];
    int t = threadIdx.x;
    int node0 = blockIdx.x * 64;
    {
        int row = t >> 2;
#pragma unroll
        for (int i = 0; i < 4; ++i) {
            int chunk = (t & 3) + i * 4;
            uint4 v;
            if constexpr (F32IN) {
                const float* s = (const float*)Xin + (size_t)(node0 + row) * 128 + chunk * 8;
                float4 v0 = *reinterpret_cast<const float4*>(s);
                float4 v1 = *reinterpret_cast<const float4*>(s + 4);
                uint* vu = reinterpret_cast<uint*>(&v);
                vu[0] = (uint)f2bf(v0.x) | ((uint)f2bf(v0.y) << 16);
                vu[1] = (uint)f2bf(v0.z) | ((uint)f2bf(v0.w) << 16);
                vu[2] = (uint)f2bf(v1.x) | ((uint)f2bf(v1.y) << 16);
                vu[3] = (uint)f2bf(v1.z) | ((uint)f2bf(v1.w) << 16);
            } else {
                v = *reinterpret_cast<const uint4*>((const ushort*)Xin + (size_t)(node0 + row) * 128 + chunk * 8);
            }
            xt[row * 17 + chunk] = v;
        }
    }
    __syncthreads();

    int lane = t & 63, wv = t >> 6;
    int lr = lane & 15, lg = lane >> 4;

    // B-frags: 4 rowsets x 4 k-chunks, loaded once, reused for all col-blocks
    bf16x8 bf[4][4];
#pragma unroll
    for (int rs = 0; rs < 4; ++rs)
#pragma unroll
        for (int kk = 0; kk < 4; ++kk)
            bf[rs][kk] = *reinterpret_cast<const bf16x8*>(&xt[(rs * 16 + lr) * 17 + lg + 4 * kk]);

    float degf[4];
    if constexpr (DEGBIAS) {
#pragma unroll
        for (int rs = 0; rs < 4; ++rs) {
            int r_ = node0 + rs * 16 + lr;
            degf[rs] = (float)(rp[r_ + 1] - rp[r_]);
        }
    }

    constexpr int NBW = NOUT / 64;  // col-blocks per wave
#pragma unroll
    for (int q = 0; q < NBW; ++q) {
        int nb = wv * NBW + q;
        const ushort* wrow = Wt + (size_t)(nb * 16 + lr) * 128 + lg * 8;
        bf16x8 af[4];
#pragma unroll
        for (int kk = 0; kk < 4; ++kk) af[kk] = *reinterpret_cast<const bf16x8*>(wrow + kk * 32);
        float4 bb = *reinterpret_cast<const float4*>(bias + nb * 16 + lg * 4);
        const float* bbp = reinterpret_cast<const float*>(&bb);
#pragma unroll
        for (int rs = 0; rs < 4; ++rs) {
            f32x4 acc = {0.f, 0.f, 0.f, 0.f};
#pragma unroll
            for (int kk = 0; kk < 4; ++kk)
                acc = __builtin_amdgcn_mfma_f32_16x16x32_bf16(af[kk], bf[rs][kk], acc, 0, 0, 0);
            ushort4 o;
#pragma unroll
            for (int r = 0; r < 4; ++r) {
                float v = acc[r] + (DEGBIAS ? degf[rs] * bbp[r] : bbp[r]);
                if constexpr (RELU) v = fmaxf(v, 0.f);
                reinterpret_cast<ushort*>(&o)[r] = f2bf(v);
            }
            *reinterpret_cast<ushort4*>(Y + (size_t)(node0 + rs * 16 + lr) * NOUT + nb * 16 + lg * 4) = o;
        }
    }
}

// ---------------- edge aggregation: Hagg[n] = sum relu(A[n] + B[src]) (wave per node) -------
__device__ inline void accum8(uint4 b, const float2* a, float2* acc) {
    const uint* bu = reinterpret_cast<const uint*>(&b);
#pragma unroll
    for (int j = 0; j < 4; ++j) {
        uint u = bu[j];
        acc[j].x += fmaxf(a[j].x + bf2f(u), 0.f);
        acc[j].y += fmaxf(a[j].y + bf2f_hi(u), 0.f);
    }
}

__global__ __launch_bounds__(256) void agg_k(const ushort* __restrict__ AB,
                                             const int* __restrict__ rp, const int* __restrict__ col,
                                             ushort* __restrict__ Hagg, int M) {
    int wave = threadIdx.x >> 6;
    int lane = threadIdx.x & 63;
    int n = blockIdx.x * 4 + wave;
    if (n >= M) return;
    int fs = lane & 15;
    int lg = lane >> 4;

    uint4 av = *reinterpret_cast<const uint4*>(AB + (size_t)n * 256 + fs * 8);
    float2 a[4];
    {
        const uint* au = reinterpret_cast<const uint*>(&av);
#pragma unroll
        for (int j = 0; j < 4; ++j) a[j] = make_float2(bf2f(au[j]), bf2f_hi(au[j]));
    }
    float2 acc[4] = {{0.f, 0.f}, {0.f, 0.f}, {0.f, 0.f}, {0.f, 0.f}};

    int e0 = rp[n], e1 = rp[n + 1];
    int eMain = e0 + ((e1 - e0) & ~7);

    for (int eb = e0; eb < eMain; eb += 8) {
        int sA = col[eb + lg];
        int sB = col[eb + lg + 4];
        uint4 bA = *reinterpret_cast<const uint4*>(AB + (size_t)sA * 256 + 128 + fs * 8);
        uint4 bB = *reinterpret_cast<const uint4*>(AB + (size_t)sB * 256 + 128 + fs * 8);
        accum8(bA, a, acc);
        accum8(bB, a, acc);
    }
    for (int e = eMain + lg; e < e1; e += 4) {
        int s = col[e];
        uint4 b = *reinterpret_cast<const uint4*>(AB + (size_t)s * 256 + 128 + fs * 8);
        accum8(b, a, acc);
    }

#pragma unroll
    for (int j = 0; j < 4; ++j) {
        acc[j].x += __shfl_xor(acc[j].x, 16);
        acc[j].y += __shfl_xor(acc[j].y, 16);
        acc[j].x += __shfl_xor(acc[j].x, 32);
        acc[j].y += __shfl_xor(acc[j].y, 32);
    }
    if (lg == 0) {
        uint4 o;
        uint* ou = reinterpret_cast<uint*>(&o);
#pragma unroll
        for (int j = 0; j < 4; ++j)
            ou[j] = (uint)f2bf(acc[j].x) | ((uint)f2bf(acc[j].y) << 16);
        *reinterpret_cast<uint4*>(Hagg + (size_t)n * 128 + fs * 8) = o;
    }
}

// ---------------- pooling (node-parallel, sorted batch, atomic flush at boundaries) ----------
__global__ __launch_bounds__(128) void pool_k(const ushort* __restrict__ H, const int* __restrict__ batch,
                                              float* __restrict__ psum, int M, int nblk) {
    int f = threadIdx.x;
    int chunk = (M + nblk - 1) / nblk;
    int n0 = blockIdx.x * chunk;
    int n1 = n0 + chunk;
    if (n1 > M) n1 = M;
    if (n0 >= n1) return;
    int g = batch[n0];
    float acc = 0.f;
    for (int n = n0; n < n1; ++n) {
        int bg = batch[n];
        if (bg != g) {
            atomicAdd(&psum[g * 128 + f], acc);
            acc = 0.f;
            g = bg;
        }
        acc += bf2f((uint)H[(size_t)n * 128 + f]);
    }
    atomicAdd(&psum[g * 128 + f], acc);
}

// ---------------- head MLP ----------------
__global__ __launch_bounds__(128) void head_k(const float* __restrict__ psum,
                                              const int* __restrict__ gs,
                                              const float* __restrict__ wm1, const float* __restrict__ bm1,
                                              const float* __restrict__ wm2, const float* __restrict__ bm2,
                                              float* __restrict__ out) {
    __shared__ float p[128];
    __shared__ float h[128];
    int g = blockIdx.x, t = threadIdx.x;
    int cnt = gs[g + 1] - gs[g];
    float rcp = 1.0f / (float)(cnt > 0 ? cnt : 1);
    p[t] = psum[g * 128 + t] * rcp;
    __syncthreads();
    float a = bm1[t];
    for (int k = 0; k < 128; ++k) a += p[k] * wm1[k * 128 + t];
    h[t] = fmaxf(a, 0.f);
    __syncthreads();
    float acc[4];
#pragma unroll
    for (int j = 0; j < 4; ++j) acc[j] = bm2[j * 128 + t];
    for (int k = 0; k < 128; ++k) {
        float hv = h[k];
#pragma unroll
        for (int j = 0; j < 4; ++j) acc[j] += hv * wm2[k * 512 + j * 128 + t];
    }
#pragma unroll
    for (int j = 0; j < 4; ++j) out[(size_t)g * 512 + j * 128 + t] = acc[j];
}

extern "C" void kernel_launch(void* const* d_in, const int* in_sizes, int n_in,
                              void* d_out, int out_size, void* d_ws, size_t ws_size,
                              hipStream_t stream) {
    const float* x = (const float*)d_in[0];
    const int* ei = (const int*)d_in[1];
    const int* batch = (const int*)d_in[2];
    const float* w1_1 = (const float*)d_in[3];
    const float* b1_1 = (const float*)d_in[4];
    const float* w1_2 = (const float*)d_in[5];
    const float* b1_2 = (const float*)d_in[6];
    const float* w2_1 = (const float*)d_in[7];
    const float* b2_1 = (const float*)d_in[8];
    const float* w2_2 = (const float*)d_in[9];
    const float* b2_2 = (const float*)d_in[10];
    const float* wm1 = (const float*)d_in[11];
    const float* bm1 = (const float*)d_in[12];
    const float* wm2 = (const float*)d_in[13];
    const float* bm2 = (const float*)d_in[14];

    const int E = in_sizes[1] / 2;
    const int M = in_sizes[0] / 128;
    const int* srcp = ei;
    const int* dstp = ei + E;

    char* ws = (char*)d_ws;
    size_t off = 0;
    auto alloc = [&](size_t bytes) -> void* {
        void* p = ws + off;
        off += (bytes + 255) & ~(size_t)255;
        return p;
    };
    ushort* AB1 = (ushort*)alloc((size_t)M * 256 * 2);
    ushort* AB2 = (ushort*)alloc((size_t)M * 256 * 2);
    ushort* Hagg = (ushort*)alloc((size_t)M * 128 * 2);
    ushort* H = (ushort*)alloc((size_t)M * 128 * 2);   // H1 then final H
    int* rp = (int*)alloc((size_t)(M + 1) * 4);
    int* cursor = (int*)alloc((size_t)M * 4);  // reused as deg during hist
    int* col = (int*)alloc((size_t)E * 4);
    int* gs = (int*)alloc((GRAPHS + 1) * 4);
    float* psum = (float*)alloc(GRAPHS * 128 * 4);
    ushort* wt1a = (ushort*)alloc(256 * 128 * 2);
    ushort* wt1b = (ushort*)alloc(256 * 128 * 2);
    ushort* wt2a = (ushort*)alloc(128 * 128 * 2);
    ushort* wt2b = (ushort*)alloc(128 * 128 * 2);
    float* b256_1 = (float*)alloc(256 * 4);
    float* b256_2 = (float*)alloc(256 * 4);

    const int nbDeg = (M + 255) / 256;

    // 1. setup (weights, deg=0, psum=0, biases, gstart)
    setup_k<<<128 + 64 + nbDeg + 32 + 2, 256, 0, stream>>>(
        w1_1, w2_1, w1_2, w2_2, b1_1, b2_1, wt1a, wt1b, wt2a, wt2b, b256_1, b256_2,
        cursor, psum, batch, gs, M, nbDeg);
    // 2-4. CSR over dst
    hist_k<<<(E + 255) / 256, 256, 0, stream>>>(dstp, cursor, E);
    scan_k<<<1, 256, 0, stream>>>(cursor, rp, cursor, M);
    fill_k<<<(E + 255) / 256, 256, 0, stream>>>(srcp, dstp, cursor, col, E);
    // 5. layer1 edge-GEMM (fp32 x in)
    ngemm_k<256, false, false, true><<<M / 64, 256, 0, stream>>>(x, wt1a, b256_1, nullptr, AB1, M);
    // 6. layer1 aggregate
    agg_k<<<(M + 3) / 4, 256, 0, stream>>>(AB1, rp, col, Hagg, M);
    // 7. layer1 H-GEMM
    ngemm_k<128, true, true, false><<<M / 64, 256, 0, stream>>>(Hagg, wt2a, b1_2, rp, H, M);
    // 8. layer2 edge-GEMM
    ngemm_k<256, false, false, false><<<M / 64, 256, 0, stream>>>(H, wt1b, b256_2, nullptr, AB2, M);
    // 9. layer2 aggregate
    agg_k<<<(M + 3) / 4, 256, 0, stream>>>(AB2, rp, col, Hagg, M);
    // 10. layer2 H-GEMM
    ngemm_k<128, true, true, false><<<M / 64, 256, 0, stream>>>(Hagg, wt2b, b2_2, rp, H, M);
    // 11-12. pool + head
    pool_k<<<512, 128, 0, stream>>>(H, batch, psum, M, 512);
    head_k<<<GRAPHS, 128, 0, stream>>>(psum, gs, wm1, bm1, wm2, bm2, (float*)d_out);
}